// Round 8
// baseline (244.904 us; speedup 1.0000x reference)
//
#include <hip/hip_runtime.h>
#include <stdint.h>

#define NB 32
#define NL 1024
#define ND 256
// attn fp32 row = 1024 f32 = 4096 B = 2048 u16 slots. Pack bf16 P in slots
// [0,1024); per-row partial sums (8 n-blocks) live in f32 slots [512,520).
#define ROWU16 2048

typedef __attribute__((ext_vector_type(8))) __bf16 bf16x8;
typedef __attribute__((ext_vector_type(8))) uint16_t u16x8;
typedef __attribute__((ext_vector_type(4))) float f32x4;

__device__ __forceinline__ uint16_t f2bf(float f) {
  union { float f; uint32_t u; } v; v.f = f;
  return (uint16_t)((v.u + 0x7fffu + ((v.u >> 16) & 1u)) >> 16);
}
__device__ __forceinline__ float bf2f(uint16_t h) {
  union { uint32_t u; float f; } v; v.u = ((uint32_t)h) << 16;
  return v.f;
}

#define GLD_LDS16(g, l)                                                        \
  __builtin_amdgcn_global_load_lds(                                            \
      (__attribute__((address_space(1))) void*)(g),                            \
      (__attribute__((address_space(3))) void*)(l), 16, 0, 0)

// ---------------------------------------------------------------------------
// Kernel 0: q fp32 -> Qb bf16 [b][l][d]  and  Qt bf16 [b][d][l]
// (memory-roofline bound — unchanged)
// ---------------------------------------------------------------------------
__global__ __launch_bounds__(256) void convert_kernel(
    const float* __restrict__ q, uint16_t* __restrict__ qb,
    uint16_t* __restrict__ qt) {
  __shared__ uint16_t tile[64][72];
  int b = blockIdx.z;
  int l0 = blockIdx.x * 64, d0 = blockIdx.y * 64;
  int t = threadIdx.x;
  int r = t >> 4;
  int c4 = (t & 15) * 4;
  const float* qsrc = q + (size_t)b * NL * ND;
  uint16_t* qbb = qb + (size_t)b * NL * ND;
  uint16_t* qtb = qt + (size_t)b * ND * NL;
#pragma unroll
  for (int i = 0; i < 4; i++) {
    int row = r + 16 * i;
    float4 v = *(const float4*)(qsrc + (size_t)(l0 + row) * ND + d0 + c4);
    ushort4 h;
    h.x = f2bf(v.x); h.y = f2bf(v.y); h.z = f2bf(v.z); h.w = f2bf(v.w);
    *(ushort4*)(qbb + (size_t)(l0 + row) * ND + d0 + c4) = h;
    tile[row][c4 + 0] = h.x; tile[row][c4 + 1] = h.y;
    tile[row][c4 + 2] = h.z; tile[row][c4 + 3] = h.w;
  }
  __syncthreads();
#pragma unroll
  for (int i = 0; i < 4; i++) {
    int drow = r + 16 * i;
    ushort4 h;
    h.x = tile[c4 + 0][drow]; h.y = tile[c4 + 1][drow];
    h.z = tile[c4 + 2][drow]; h.w = tile[c4 + 3][drow];
    *(ushort4*)(qtb + (size_t)(d0 + drow) * NL + l0 + c4) = h;
  }
}

// ---------------------------------------------------------------------------
// Kernel 1: e = exp(S/16) (s==0 -> 0), S = Qb Qb^T. Writes bf16 e packed into
// attn rows + per-(row, n-block) fp32 partial sums into spare slots.
// 128x128 tile, 256 threads, flat grid 2048 with bijective XCD swizzle.
// Epilogue: per tm-group, post-exp bf16 fragments are repacked through a
// 32x136-u16 padded LDS tile (ds_write_b16; +8 pad -> quad rows 16 banks
// apart, 2-way = free) then stored coalesced (2 x 16B per thread) instead of
// 64 scattered 2-B global stores per thread.
// ---------------------------------------------------------------------------
__global__ __launch_bounds__(256) void qk_kernel(
    const uint16_t* __restrict__ qb, float* __restrict__ attn_f32) {
  __shared__ alignas(16) uint16_t SMEM[2 * 128 * 32];  // As | Bs, reused as repack
  __shared__ float rp[128][2];
  uint16_t* As = SMEM;
  uint16_t* Bs = SMEM + 128 * 32;
  // XCD swizzle: 2048 wgs, 256 contiguous per XCD = batches [4x, 4x+4)
  int wg = (blockIdx.x & 7) * 256 + (blockIdx.x >> 3);
  int b = wg >> 6;
  int m0 = ((wg >> 3) & 7) * 128, n0 = (wg & 7) * 128;
  int nxi = wg & 7;  // n-block index (rowsum slot)
  const uint16_t* Q = qb + (size_t)b * NL * ND;
  int tid = threadIdx.x, lane = tid & 63, wave = tid >> 6;
  int wm = (wave & 1) * 64, wn = (wave >> 1) * 64;
  int quad = lane >> 4, l15 = lane & 15;
  f32x4 acc[4][4] = {};

  for (int k0 = 0; k0 < ND; k0 += 32) {
    __syncthreads();
#pragma unroll
    for (int i = 0; i < 2; i++) {
      int c = i * 256 + wave * 64 + lane;
      int row = c >> 2, cc = c & 3;
      int sw = (row >> 1) & 3;
      int gc = k0 + ((cc ^ sw) * 8);
      GLD_LDS16(Q + (size_t)(m0 + row) * ND + gc,
                As + (size_t)(i * 256 + wave * 64) * 8);
      GLD_LDS16(Q + (size_t)(n0 + row) * ND + gc,
                Bs + (size_t)(i * 256 + wave * 64) * 8);
    }
    __syncthreads();
    bf16x8 af[4], bfr[4];
#pragma unroll
    for (int t = 0; t < 4; t++) {
      int ra = wm + t * 16 + l15;
      af[t] = *(const bf16x8*)(As + ra * 32 + ((quad ^ ((ra >> 1) & 3)) * 8));
      int rb = wn + t * 16 + l15;
      bfr[t] = *(const bf16x8*)(Bs + rb * 32 + ((quad ^ ((rb >> 1) & 3)) * 8));
    }
#pragma unroll
    for (int tm = 0; tm < 4; tm++)
#pragma unroll
      for (int tn = 0; tn < 4; tn++)
        acc[tm][tn] = __builtin_amdgcn_mfma_f32_16x16x32_bf16(
            af[tm], bfr[tn], acc[tm][tn], 0, 0, 0);
  }

  const float kf = 0.09016844005555f;  // log2(e)/16
  uint16_t* attn_u16 = (uint16_t*)attn_f32;
  size_t gbase = (size_t)b * NL;
  // repack tile: 32 rows x 136 u16 (pad 8) = 8704 B, lives in SMEM
  const int RSTR = 136;
#pragma unroll
  for (int tm = 0; tm < 4; tm++) {
    __syncthreads();  // SMEM free (K-loop reads done / prev tm reads done)
    int row32 = ((wm >> 6) << 4) + quad * 4;  // + j below; 0..31
    float rsum[4] = {0.f, 0.f, 0.f, 0.f};
#pragma unroll
    for (int tn = 0; tn < 4; tn++) {
      int col = wn + tn * 16 + l15;  // 0..127
#pragma unroll
      for (int j = 0; j < 4; j++) {
        float s = acc[tm][tn][j];
        float e = (s == 0.0f) ? 0.0f : __builtin_amdgcn_exp2f(s * kf);
        union { __bf16 b; uint16_t u; } cv;
        cv.b = (__bf16)e;  // native cvt, RNE
        SMEM[(row32 + j) * RSTR + col] = cv.u;
        rsum[j] += e;
      }
    }
#pragma unroll
    for (int j = 0; j < 4; j++) {
      float v = rsum[j];
      v += __shfl_xor(v, 1, 64);
      v += __shfl_xor(v, 2, 64);
      v += __shfl_xor(v, 4, 64);
      v += __shfl_xor(v, 8, 64);
      if (l15 == 0) rp[wm + tm * 16 + quad * 4 + j][wave >> 1] = v;
    }
    __syncthreads();  // repack tile visible
    // coalesced drain: 256 threads x 32 B
    int rr = tid >> 3, c8 = tid & 7;
    int grow = m0 + ((rr >> 4) << 6) + tm * 16 + (rr & 15);
    const uint16_t* src = SMEM + rr * RSTR + c8 * 16;
    u16x8 v0 = *(const u16x8*)src;
    u16x8 v1 = *(const u16x8*)(src + 8);
    uint16_t* dst = attn_u16 + (gbase + grow) * ROWU16 + n0 + c8 * 16;
    *(u16x8*)dst = v0;
    *(u16x8*)(dst + 8) = v1;
  }
  __syncthreads();
  if (tid < 128) {
    float s = rp[tid][0] + rp[tid][1];
    attn_f32[(gbase + m0 + tid) * (size_t)NL + 512 + nxi] = s;
  }
}

// ---------------------------------------------------------------------------
// Kernel 2 (fused): out = (P @ Q) * inv_rowsum AND in-place expansion of the
// packed bf16 P rows into normalized fp32 attn rows.
// Tile 64 (m) x 256 (full D), 256 threads (4 waves). Flat grid 512 with the
// SAME XCD mapping as qk (batch b -> XCD b/4), so packed-P reads hit the L2
// that qk just wrote. Each block exclusively owns its 64 attn rows.
// K runs HIGH -> LOW; expansion of chunk k0 is computed in iteration k0 but
// stored one iteration later beside the gld_lds issue (store drain overlaps
// load drain). Deferred store range [4*k0+128, 4*k0+256) never intersects
// remaining packed reads [2*k0, 2*k0+64).
// ---------------------------------------------------------------------------
__global__ __launch_bounds__(256) void pv_kernel(
    float* __restrict__ attn_f32, const uint16_t* __restrict__ qt,
    float* __restrict__ out) {
  __shared__ alignas(16) uint16_t As[64 * 32];
  __shared__ alignas(16) uint16_t Bs[256 * 32];
  __shared__ float inv_lds[64];
  // XCD swizzle: 512 wgs, 64 contiguous per XCD = batches [4x, 4x+4)
  int wg = (blockIdx.x & 7) * 64 + (blockIdx.x >> 3);
  int b = wg >> 4;
  int m0 = (wg & 15) * 64;
  const uint16_t* Ap = (const uint16_t*)attn_f32 + (size_t)b * NL * ROWU16;
  const uint16_t* Bt = qt + (size_t)b * ND * NL;
  int tid = threadIdx.x, lane = tid & 63, wave = tid >> 6;
  int wn = wave * 64;  // wave covers cols [wn, wn+64) of D=256
  int quad = lane >> 4, l15 = lane & 15;
  f32x4 acc[4][4] = {};

  if (tid < 64) {
    const float* pf = attn_f32 + (size_t)(b * NL + m0 + tid) * NL + 512;
    float s = pf[0] + pf[1] + pf[2] + pf[3] + pf[4] + pf[5] + pf[6] + pf[7];
    inv_lds[tid] = (s > 0.0f) ? 1.0f / s : 0.0f;
  }

  // expansion assignment: 256 threads cover 64 rows x 4 chunks-of-8-u16
  int xr = tid >> 2;  // local row 0..63
  int xc = tid & 3;   // which 8-u16 chunk within the 32-u16 K-step
  int xsw = (xr >> 1) & 3;
  float* xrow = attn_f32 + (size_t)(b * NL + m0 + xr) * NL;

  float4 p0, p1;
  float* pdst = nullptr;

  for (int k0 = NL - 32; k0 >= 0; k0 -= 32) {
    __syncthreads();
    // flush previous chunk's expansion (drains together with gld_lds below)
    if (k0 != NL - 32) {
      ((float4*)pdst)[0] = p0;
      ((float4*)pdst)[1] = p1;
    }
    {
      // A: 64 rows x 32 u16 = 4 KB, one gld_lds across 256 threads
      int row = tid >> 2, cc = tid & 3;
      int sw = (row >> 1) & 3;
      int gc = k0 + ((cc ^ sw) * 8);
      GLD_LDS16(Ap + (size_t)(m0 + row) * ROWU16 + gc,
                As + (size_t)(wave * 64) * 8);
    }
#pragma unroll
    for (int i = 0; i < 4; i++) {
      // B: 256 rows x 32 u16 = 16 KB, four gld_lds across 256 threads
      int c = i * 256 + tid;
      int row = c >> 2, cc = c & 3;
      int sw = (row >> 1) & 3;
      int gc = k0 + ((cc ^ sw) * 8);
      GLD_LDS16(Bt + (size_t)row * NL + gc,
                Bs + (size_t)(i * 256 + wave * 64) * 8);
    }
    __syncthreads();
    bf16x8 af[4], bfr[4];
#pragma unroll
    for (int t = 0; t < 4; t++) {
      int ra = t * 16 + l15;
      af[t] = *(const bf16x8*)(As + ra * 32 + ((quad ^ ((ra >> 1) & 3)) * 8));
      int rb = wn + t * 16 + l15;
      bfr[t] = *(const bf16x8*)(Bs + rb * 32 + ((quad ^ ((rb >> 1) & 3)) * 8));
    }
#pragma unroll
    for (int tm = 0; tm < 4; tm++)
#pragma unroll
      for (int tn = 0; tn < 4; tn++)
        acc[tm][tn] = __builtin_amdgcn_mfma_f32_16x16x32_bf16(
            af[tm], bfr[tn], acc[tm][tn], 0, 0, 0);

    // compute this chunk's expansion into registers (reads As; valid until
    // the next top-of-loop barrier). Store happens next iteration.
    {
      u16x8 hv = *(const u16x8*)(As + xr * 32 + ((xc ^ xsw) * 8));
      float inv = inv_lds[xr];
      p0.x = bf2f(hv[0]) * inv;
      p0.y = bf2f(hv[1]) * inv;
      p0.z = bf2f(hv[2]) * inv;
      p0.w = bf2f(hv[3]) * inv;
      p1.x = bf2f(hv[4]) * inv;
      p1.y = bf2f(hv[5]) * inv;
      p1.z = bf2f(hv[6]) * inv;
      p1.w = bf2f(hv[7]) * inv;
      pdst = xrow + k0 + xc * 8;
    }
  }
  // final flush (chunk k0 = 0)
  ((float4*)pdst)[0] = p0;
  ((float4*)pdst)[1] = p1;

  float* O = out + (size_t)b * NL * ND;
#pragma unroll
  for (int tm = 0; tm < 4; tm++) {
    int rbl = tm * 16 + quad * 4;
#pragma unroll
    for (int tn = 0; tn < 4; tn++) {
      int col = wn + tn * 16 + l15;
#pragma unroll
      for (int j = 0; j < 4; j++)
        O[(size_t)(m0 + rbl + j) * ND + col] = acc[tm][tn][j] * inv_lds[rbl + j];
    }
  }
}

// ---------------------------------------------------------------------------
extern "C" void kernel_launch(void* const* d_in, const int* in_sizes, int n_in,
                              void* d_out, int out_size, void* d_ws,
                              size_t ws_size, hipStream_t stream) {
  (void)in_sizes; (void)n_in; (void)out_size; (void)ws_size;
  const float* q = (const float*)d_in[0];
  float* out = (float*)d_out;
  float* attn = out + (size_t)NB * NL * ND;  // [output | attn] concat
  uint16_t* qb = (uint16_t*)d_ws;            // 16 MiB
  uint16_t* qt = qb + (size_t)NB * NL * ND;  // 16 MiB

  convert_kernel<<<dim3(16, 4, NB), 256, 0, stream>>>(q, qb, qt);
  qk_kernel<<<dim3(2048, 1, 1), 256, 0, stream>>>(qb, attn);
  pv_kernel<<<dim3(512, 1, 1), 256, 0, stream>>>(attn, qt, out);
}